// Round 6
// baseline (294.144 us; speedup 1.0000x reference)
//
#include <hip/hip_runtime.h>
#include <hip/hip_bf16.h>

typedef __attribute__((ext_vector_type(8))) short bf16x8;
typedef __attribute__((ext_vector_type(4))) float f32x4;
typedef __attribute__((ext_vector_type(16))) float f32x16;

#define GLOBAL_CAST(p) (const __attribute__((address_space(1))) void*)(p)
#define LDS_CAST(p)    (__attribute__((address_space(3))) void*)(p)

static __device__ __forceinline__ unsigned short f2bf(float f) {
    union { float f; unsigned int u; } v; v.f = f;
    unsigned int u = v.u;
    unsigned int r = (u + 0x7FFFu + ((u >> 16) & 1u)) >> 16;   // RNE
    return (unsigned short)r;
}

// ---------------------------------------------------------------------------
// Kernel 1: per-row scale = max(mean(|w|), eps); q = ternary(w) as bf16 bits.
// ---------------------------------------------------------------------------
__global__ __launch_bounds__(256) void scale_quant_kernel(
    const float* __restrict__ w, float* __restrict__ scale,
    unsigned short* __restrict__ q, int K)
{
    const int row = blockIdx.x;
    const int tid = threadIdx.x;
    const float* wrow = w + (size_t)row * K;

    float s = 0.f;
    const int nvec = K >> 2;
    const float4* wv = (const float4*)wrow;
    for (int i = tid; i < nvec; i += blockDim.x) {
        float4 v = wv[i];
        s += fabsf(v.x) + fabsf(v.y) + fabsf(v.z) + fabsf(v.w);
    }
    #pragma unroll
    for (int off = 32; off > 0; off >>= 1) s += __shfl_down(s, off);

    __shared__ float red[4];
    const int lane = tid & 63, wid = tid >> 6;
    if (lane == 0) red[wid] = s;
    __syncthreads();
    const float total = red[0] + red[1] + red[2] + red[3];
    const float sc = fmaxf(total / (float)K, 1e-6f);
    const float thr = sc * 0.75f;
    if (tid == 0) scale[row] = sc;

    if (q != nullptr) {
        ushort4* qv = (ushort4*)(q + (size_t)row * K);
        for (int i = tid; i < nvec; i += blockDim.x) {
            float4 v = wv[i];
            ushort4 o;
            o.x = (v.x >= thr) ? 0x3F80u : ((v.x <= -thr) ? 0xBF80u : 0u);
            o.y = (v.y >= thr) ? 0x3F80u : ((v.y <= -thr) ? 0xBF80u : 0u);
            o.z = (v.z >= thr) ? 0x3F80u : ((v.z <= -thr) ? 0xBF80u : 0u);
            o.w = (v.w >= thr) ? 0x3F80u : ((v.w <= -thr) ? 0xBF80u : 0u);
            qv[i] = o;
        }
    }
}

// ---------------------------------------------------------------------------
// Kernel 2: x fp32 -> bf16 (RNE), 8 elems/thread.
// ---------------------------------------------------------------------------
__global__ __launch_bounds__(256) void convert_x_kernel(
    const float* __restrict__ x, unsigned short* __restrict__ xb, long n)
{
    long i = ((long)blockIdx.x * blockDim.x + threadIdx.x) * 8;
    if (i + 8 > n) return;
    float4 a = *(const float4*)(x + i);
    float4 b = *(const float4*)(x + i + 4);
    ushort4 lo, hi;
    lo.x = f2bf(a.x); lo.y = f2bf(a.y); lo.z = f2bf(a.z); lo.w = f2bf(a.w);
    hi.x = f2bf(b.x); hi.y = f2bf(b.y); hi.z = f2bf(b.z); hi.w = f2bf(b.w);
    *(ushort4*)(xb + i)     = lo;
    *(ushort4*)(xb + i + 4) = hi;
}

// ---------------------------------------------------------------------------
// Kernel 3: 256x256 bf16 GEMM, 32x32x16 MFMA, 2 barriers / K-tile (r4 sched).
//   out[m][n] = scale[n] * sum_k Xb[m][k]*Qb[n][k] + bias[n]
// 512 thr = 8 waves (2M x 4N); per-wave 128x64 out = acc[4][2] 32x32 frags,
// K-tile (64) consumed as 4 k-slices of 16.
// LDS 128 KiB: 2 dbuf x {A 256x64, B 256x64} bf16, chunk-slot XOR swizzle
// (LDS slot s of row r holds global k-chunk s^(r&7)).
// Per K-tile t: sec A { stage A(t+1)->ta | ks0 reads+8 MFMA |
//                       stage B(t+1)->ta | ks1 reads+8 MFMA } bar
//               sec B { ks2 reads+8 MFMA | ks3 reads+8 MFMA } vmcnt(0) bar
// Operand layout (32x32x16): lane holds row l&31, k=(l>>5)*8+i.
// C/D layout: col=lane&31, row=(reg&3)+8*(reg>>2)+4*(lane>>5)  [m74/m101].
// ---------------------------------------------------------------------------
#define BM 256
#define BN 256
#define BK 64

__global__ __launch_bounds__(512, 2) void gemm256_kernel(
    const unsigned short* __restrict__ Xb,   // [M][K] bf16 bits
    const unsigned short* __restrict__ Qb,   // [N][K] bf16 bits
    const float* __restrict__ scale,
    const float* __restrict__ bias,
    float* __restrict__ out, int M, int N, int K)
{
    __shared__ __align__(16) char lds[131072];

    const int tid  = threadIdx.x;
    const int lane = tid & 63;
    const int wid  = tid >> 6;       // 0..7
    const int wm   = wid >> 2;       // 0..1  (M half of tile)
    const int wn   = wid & 3;        // 0..3  (N quarter)
    const int l31  = lane & 31;

    // XCD-bijective swizzle (grid % 8 == 0 guaranteed by host gate)
    int bid = blockIdx.x;
    const int nwg = gridDim.x;
    if ((nwg & 7) == 0) { const int cpx = nwg >> 3; bid = (bid & 7) * cpx + (bid >> 3); }
    const int nbn = N / BN;
    const int tm = bid / nbn, tn = bid % nbn;
    const int arow0 = tm * BM;
    const int brow0 = tn * BN;
    const int NT = K / BK;

    // ---- LDS read addressing: addr = tb | base[frag] | psel[ks] ----
    // base = row*128 (row-aligned); psel = ((ks*2 + kg)*16) ^ ((row&7)*16)
    const unsigned arx = (unsigned)((lane & 7) << 4);          // (row&7)*16
    const unsigned kgb = (unsigned)(((lane >> 5) & 1) << 4);   // kg*16
    unsigned psel[4];
    #pragma unroll
    for (int ks = 0; ks < 4; ++ks) psel[ks] = (((unsigned)ks << 5) | kgb) ^ arx;
    unsigned abase[4], bbase[2];
    #pragma unroll
    for (int mf = 0; mf < 4; ++mf) abase[mf] = (unsigned)((wm * 128 + mf * 32 + l31) * 128);
    #pragma unroll
    for (int nf = 0; nf < 2; ++nf) bbase[nf] = (unsigned)(32768 + (wn * 64 + nf * 32 + l31) * 128);

    // ---- stage streams: 8 running global pointers + fixed LDS dest offs ----
    const int r0 = tid >> 3,        c0 = (((tid & 7) ^ (r0 & 7)) << 3);
    const int ci1 = 512 + tid;
    const int r1 = ci1 >> 3,        c1 = (((ci1 & 7) ^ (r1 & 7)) << 3);

    const unsigned short* asrc[2][2];
    const unsigned short* bsrc[2][2];
    unsigned adst[2][2], bdst[2][2];
    #pragma unroll
    for (int hh = 0; hh < 2; ++hh) {
        asrc[hh][0] = Xb + (size_t)(arow0 + hh * 128 + r0) * K + BK + c0;   // A(t+1)
        asrc[hh][1] = Xb + (size_t)(arow0 + hh * 128 + r1) * K + BK + c1;
        bsrc[hh][0] = Qb + (size_t)(brow0 + hh * 128 + r0) * K + BK + c0;   // B(t+1)
        bsrc[hh][1] = Qb + (size_t)(brow0 + hh * 128 + r1) * K + BK + c1;
        adst[hh][0] = (unsigned)(hh * 16384 + tid * 16);
        adst[hh][1] = (unsigned)(hh * 16384 + ci1 * 16);
        bdst[hh][0] = (unsigned)(32768 + hh * 16384 + tid * 16);
        bdst[hh][1] = (unsigned)(32768 + hh * 16384 + ci1 * 16);
    }

    // ---- prologue: stage tile 0 {A0,A1,B0,B1} into buffer 0 ----
    #pragma unroll
    for (int hh = 0; hh < 2; ++hh) {
        const int rowA = arow0 + hh * 128, rowB = brow0 + hh * 128;
        const unsigned short* ga0 = Xb + (size_t)(rowA + r0) * K + c0;
        const unsigned short* ga1 = Xb + (size_t)(rowA + r1) * K + c1;
        const unsigned short* gb0 = Qb + (size_t)(rowB + r0) * K + c0;
        const unsigned short* gb1 = Qb + (size_t)(rowB + r1) * K + c1;
        __builtin_amdgcn_global_load_lds(GLOBAL_CAST(ga0), LDS_CAST(lds + adst[hh][0]), 16, 0, 0);
        __builtin_amdgcn_global_load_lds(GLOBAL_CAST(ga1), LDS_CAST(lds + adst[hh][1]), 16, 0, 0);
        __builtin_amdgcn_global_load_lds(GLOBAL_CAST(gb0), LDS_CAST(lds + bdst[hh][0]), 16, 0, 0);
        __builtin_amdgcn_global_load_lds(GLOBAL_CAST(gb1), LDS_CAST(lds + bdst[hh][1]), 16, 0, 0);
    }
    asm volatile("s_waitcnt vmcnt(0)" ::: "memory");
    __builtin_amdgcn_sched_barrier(0);
    __builtin_amdgcn_s_barrier();

    f32x16 acc[4][2] = {};
    bf16x8 aX[4], bX[2], aY[4], bY[2];

    #define RDSLICE(AV, BV, KS) {                                               \
        _Pragma("unroll")                                                       \
        for (int mf = 0; mf < 4; ++mf)                                          \
            AV[mf] = *(const bf16x8*)(lds + (tb | abase[mf] | psel[KS]));       \
        _Pragma("unroll")                                                       \
        for (int nf = 0; nf < 2; ++nf)                                          \
            BV[nf] = *(const bf16x8*)(lds + (tb | bbase[nf] | psel[KS])); }
    #define MFMA8(AV, BV)                                                       \
        _Pragma("unroll")                                                       \
        for (int mf = 0; mf < 4; ++mf)                                          \
            _Pragma("unroll")                                                   \
            for (int nf = 0; nf < 2; ++nf)                                      \
                acc[mf][nf] = __builtin_amdgcn_mfma_f32_32x32x16_bf16(          \
                    AV[mf], BV[nf], acc[mf][nf], 0, 0, 0);

    for (int t = 0; t < NT; ++t) {
        const unsigned tb = (unsigned)(t & 1) << 16;
        const unsigned ta = tb ^ 0x10000u;
        const bool doS = (t < NT - 1);

        // ================= section A =================
        if (doS) {
            #pragma unroll
            for (int hh = 0; hh < 2; ++hh) {
                __builtin_amdgcn_global_load_lds(GLOBAL_CAST(asrc[hh][0]), LDS_CAST(lds + (ta | adst[hh][0])), 16, 0, 0);
                __builtin_amdgcn_global_load_lds(GLOBAL_CAST(asrc[hh][1]), LDS_CAST(lds + (ta | adst[hh][1])), 16, 0, 0);
            }
        }
        RDSLICE(aX, bX, 0)
        __builtin_amdgcn_s_setprio(1);
        MFMA8(aX, bX)
        __builtin_amdgcn_s_setprio(0);

        if (doS) {
            #pragma unroll
            for (int hh = 0; hh < 2; ++hh) {
                __builtin_amdgcn_global_load_lds(GLOBAL_CAST(bsrc[hh][0]), LDS_CAST(lds + (ta | bdst[hh][0])), 16, 0, 0);
                __builtin_amdgcn_global_load_lds(GLOBAL_CAST(bsrc[hh][1]), LDS_CAST(lds + (ta | bdst[hh][1])), 16, 0, 0);
            }
        }
        RDSLICE(aY, bY, 1)
        __builtin_amdgcn_s_setprio(1);
        MFMA8(aY, bY)
        __builtin_amdgcn_s_setprio(0);

        __builtin_amdgcn_s_barrier();

        // ================= section B =================
        RDSLICE(aX, bX, 2)
        __builtin_amdgcn_s_setprio(1);
        MFMA8(aX, bX)
        __builtin_amdgcn_s_setprio(0);

        RDSLICE(aY, bY, 3)
        __builtin_amdgcn_s_setprio(1);
        MFMA8(aY, bY)
        __builtin_amdgcn_s_setprio(0);

        // advance stage streams (BK elements = 128 B)
        #pragma unroll
        for (int hh = 0; hh < 2; ++hh) {
            asrc[hh][0] += BK; asrc[hh][1] += BK;
            bsrc[hh][0] += BK; bsrc[hh][1] += BK;
        }
        asm volatile("s_waitcnt vmcnt(0)" ::: "memory");
        __builtin_amdgcn_sched_barrier(0);
        __builtin_amdgcn_s_barrier();
    }
    #undef RDSLICE
    #undef MFMA8

    // epilogue: out = scale[n]*acc + bias[n]
    // C/D: col = lane&31, row = (reg&3) + 8*(reg>>2) + 4*(lane>>5)
    #pragma unroll
    for (int nf = 0; nf < 2; ++nf) {
        const int gn = brow0 + wn * 64 + nf * 32 + l31;
        const float sc = scale[gn];
        const float bs = bias[gn];
        #pragma unroll
        for (int mf = 0; mf < 4; ++mf) {
            const size_t gm0 = (size_t)arow0 + wm * 128 + mf * 32 + ((lane >> 5) << 2);
            #pragma unroll
            for (int reg = 0; reg < 16; ++reg) {
                const int row = (reg & 3) + ((reg >> 2) << 3);
                out[(gm0 + row) * (size_t)N + gn] = acc[mf][nf][reg] * sc + bs;
            }
        }
    }
}

// ---------------------------------------------------------------------------
// Fallback: fp32 smem-tiled GEMM, quantize on the fly.
// ---------------------------------------------------------------------------
__global__ __launch_bounds__(256) void fb_gemm_kernel(
    const float* __restrict__ X, const float* __restrict__ W,
    const float* __restrict__ scale, const float* __restrict__ bias,
    float* __restrict__ out, int M, int N, int K)
{
    __shared__ float xs[16][16];
    __shared__ float qs[16][17];
    const int tx = threadIdx.x & 15, ty = threadIdx.x >> 4;
    const int m = blockIdx.y * 16 + ty;
    const int n = blockIdx.x * 16 + tx;
    const int nrow = blockIdx.x * 16 + ty;
    const int mL = min(m, M - 1);
    const int nrowL = min(nrow, N - 1);
    const float thr = scale[nrowL] * 0.75f;
    float acc = 0.f;
    for (int k0 = 0; k0 < K; k0 += 16) {
        xs[ty][tx] = X[(size_t)mL * K + k0 + tx];
        const float w = W[(size_t)nrowL * K + k0 + tx];
        qs[ty][tx] = (w >= thr) ? 1.f : ((w <= -thr) ? -1.f : 0.f);
        __syncthreads();
        #pragma unroll
        for (int kk = 0; kk < 16; ++kk) acc += xs[ty][kk] * qs[tx][kk];
        __syncthreads();
    }
    if (m < M && n < N) out[(size_t)m * N + n] = scale[n] * acc + bias[n];
}

// ---------------------------------------------------------------------------
extern "C" void kernel_launch(void* const* d_in, const int* in_sizes, int n_in,
                              void* d_out, int out_size, void* d_ws, size_t ws_size,
                              hipStream_t stream)
{
    const float* x    = (const float*)d_in[0];
    const float* w    = (const float*)d_in[1];
    const float* bias = (const float*)d_in[2];
    float* out = (float*)d_out;

    const int N = in_sizes[2];             // OUT
    const int K = in_sizes[1] / N;         // IN
    const int M = in_sizes[0] / K;         // B

    const size_t scaleBytes = (size_t)N * sizeof(float);
    const size_t qOff = (scaleBytes + 255) & ~(size_t)255;
    const size_t xOff = qOff + (size_t)N * K * sizeof(unsigned short);
    const size_t need = xOff + (size_t)M * K * sizeof(unsigned short);

    float* scale = (float*)d_ws;

    const bool fast = (ws_size >= need) &&
                      (M % BM == 0) && (N % BN == 0) && (K % BK == 0) &&
                      (K / BK >= 4) &&
                      (((M / BM) * (N / BN)) % 8 == 0);

    if (fast) {
        unsigned short* q  = (unsigned short*)((char*)d_ws + qOff);
        unsigned short* xb = (unsigned short*)((char*)d_ws + xOff);

        scale_quant_kernel<<<N, 256, 0, stream>>>(w, scale, q, K);

        const long nx = (long)M * K;
        const int cvtBlocks = (int)((nx + 2047) / 2048);
        convert_x_kernel<<<cvtBlocks, 256, 0, stream>>>(x, xb, nx);

        const int grid = (M / BM) * (N / BN);
        gemm256_kernel<<<grid, 512, 0, stream>>>(xb, q, scale, bias, out, M, N, K);
    } else {
        scale_quant_kernel<<<N, 256, 0, stream>>>(w, scale, nullptr, K);
        dim3 g((N + 15) / 16, (M + 15) / 16);
        fb_gemm_kernel<<<g, 256, 0, stream>>>(x, w, scale, bias, out, M, N, K);
    }
}

// Round 7
// 292.051 us; speedup vs baseline: 1.0072x; 1.0072x over previous
//
#include <hip/hip_runtime.h>
#include <hip/hip_bf16.h>

typedef __attribute__((ext_vector_type(8))) short bf16x8;
typedef __attribute__((ext_vector_type(4))) float f32x4;
typedef __attribute__((ext_vector_type(16))) float f32x16;

#define GLOBAL_CAST(p) (const __attribute__((address_space(1))) void*)(p)
#define LDS_CAST(p)    (__attribute__((address_space(3))) void*)(p)

static __device__ __forceinline__ unsigned short f2bf(float f) {
    union { float f; unsigned int u; } v; v.f = f;
    unsigned int u = v.u;
    unsigned int r = (u + 0x7FFFu + ((u >> 16) & 1u)) >> 16;   // RNE
    return (unsigned short)r;
}

// ---------------------------------------------------------------------------
// Kernel 1: per-row scale = max(mean(|w|), eps); q = ternary(w) as bf16 bits.
// ---------------------------------------------------------------------------
__global__ __launch_bounds__(256) void scale_quant_kernel(
    const float* __restrict__ w, float* __restrict__ scale,
    unsigned short* __restrict__ q, int K)
{
    const int row = blockIdx.x;
    const int tid = threadIdx.x;
    const float* wrow = w + (size_t)row * K;

    float s = 0.f;
    const int nvec = K >> 2;
    const float4* wv = (const float4*)wrow;
    for (int i = tid; i < nvec; i += blockDim.x) {
        float4 v = wv[i];
        s += fabsf(v.x) + fabsf(v.y) + fabsf(v.z) + fabsf(v.w);
    }
    #pragma unroll
    for (int off = 32; off > 0; off >>= 1) s += __shfl_down(s, off);

    __shared__ float red[4];
    const int lane = tid & 63, wid = tid >> 6;
    if (lane == 0) red[wid] = s;
    __syncthreads();
    const float total = red[0] + red[1] + red[2] + red[3];
    const float sc = fmaxf(total / (float)K, 1e-6f);
    const float thr = sc * 0.75f;
    if (tid == 0) scale[row] = sc;

    if (q != nullptr) {
        ushort4* qv = (ushort4*)(q + (size_t)row * K);
        for (int i = tid; i < nvec; i += blockDim.x) {
            float4 v = wv[i];
            ushort4 o;
            o.x = (v.x >= thr) ? 0x3F80u : ((v.x <= -thr) ? 0xBF80u : 0u);
            o.y = (v.y >= thr) ? 0x3F80u : ((v.y <= -thr) ? 0xBF80u : 0u);
            o.z = (v.z >= thr) ? 0x3F80u : ((v.z <= -thr) ? 0xBF80u : 0u);
            o.w = (v.w >= thr) ? 0x3F80u : ((v.w <= -thr) ? 0xBF80u : 0u);
            qv[i] = o;
        }
    }
}

// ---------------------------------------------------------------------------
// Kernel 2: x fp32 -> bf16 (RNE), 8 elems/thread.
// ---------------------------------------------------------------------------
__global__ __launch_bounds__(256) void convert_x_kernel(
    const float* __restrict__ x, unsigned short* __restrict__ xb, long n)
{
    long i = ((long)blockIdx.x * blockDim.x + threadIdx.x) * 8;
    if (i + 8 > n) return;
    float4 a = *(const float4*)(x + i);
    float4 b = *(const float4*)(x + i + 4);
    ushort4 lo, hi;
    lo.x = f2bf(a.x); lo.y = f2bf(a.y); lo.z = f2bf(a.z); lo.w = f2bf(a.w);
    hi.x = f2bf(b.x); hi.y = f2bf(b.y); hi.z = f2bf(b.z); hi.w = f2bf(b.w);
    *(ushort4*)(xb + i)     = lo;
    *(ushort4*)(xb + i + 4) = hi;
}

// ---------------------------------------------------------------------------
// Kernel 3: 256x256 bf16 GEMM, 32x32x16 MFMA, 2 barriers / K-tile.
//   out[m][n] = scale[n] * sum_k Xb[m][k]*Qb[n][k] + bias[n]
// 512 thr = 8 waves (2M x 4N); per-wave 128x64 out = acc[4][2] 32x32 frags,
// K-tile (64) consumed as 4 k-slices of 16.
// LDS 128 KiB: 2 dbuf x {A 256x64, B 256x64} bf16.
// Chunk swizzle (both sides): slot s of row r holds global chunk s ^ m(r),
//   m(r) = (r&7) ^ ((r>>3)&7).
// Rationale: bank group of a 16B chunk = 4*slot mod 32 (row drops out), so
// the slot permutation must separate lanes with equal lane&7 across row
// octaves -> include (r>>3)&7 in the XOR. Worst aliasing is 2-way (free).
// Per K-tile t: sec A { stage A(t+1)->ta | ks0 rd+8 MFMA |
//                       stage B(t+1)->ta | ks1 rd+8 MFMA } bar
//               sec B { ks2 rd+8 MFMA | ks3 rd+8 MFMA } vmcnt(0) bar
// Operand layout (32x32x16): lane holds row l&31, k=(l>>5)*8+i.
// C/D layout: col=lane&31, row=(reg&3)+8*(reg>>2)+4*(lane>>5)  [m74/m101].
// ---------------------------------------------------------------------------
#define BM 256
#define BN 256
#define BK 64

__global__ __launch_bounds__(512, 2) void gemm256_kernel(
    const unsigned short* __restrict__ Xb,   // [M][K] bf16 bits
    const unsigned short* __restrict__ Qb,   // [N][K] bf16 bits
    const float* __restrict__ scale,
    const float* __restrict__ bias,
    float* __restrict__ out, int M, int N, int K)
{
    __shared__ __align__(16) char lds[131072];

    const int tid  = threadIdx.x;
    const int lane = tid & 63;
    const int wid  = tid >> 6;       // 0..7
    const int wm   = wid >> 2;       // 0..1  (M half of tile)
    const int wn   = wid & 3;        // 0..3  (N quarter)
    const int l31  = lane & 31;

    // XCD-bijective swizzle (grid % 8 == 0 guaranteed by host gate)
    int bid = blockIdx.x;
    const int nwg = gridDim.x;
    if ((nwg & 7) == 0) { const int cpx = nwg >> 3; bid = (bid & 7) * cpx + (bid >> 3); }
    const int nbn = N / BN;
    const int tm = bid / nbn, tn = bid % nbn;
    const int arow0 = tm * BM;
    const int brow0 = tn * BN;
    const int NT = K / BK;

    // ---- LDS read addressing: addr = (tb | base_with_m[frag]) ^ ksel[ks] ----
    // base_with_m = row*128 | (m(row)<<4);  ksel = ((2ks+kg)<<4)
    const unsigned kgb = (unsigned)(((lane >> 5) & 1) << 4);
    unsigned ksel[4];
    #pragma unroll
    for (int ks = 0; ks < 4; ++ks) ksel[ks] = ((unsigned)ks << 5) | kgb;
    unsigned abx[4], bbx[2];
    #pragma unroll
    for (int mf = 0; mf < 4; ++mf) {
        const int row = wm * 128 + mf * 32 + l31;
        const unsigned m = (unsigned)((((row & 7) ^ ((row >> 3) & 7))) << 4);
        abx[mf] = (unsigned)(row * 128) | m;
    }
    #pragma unroll
    for (int nf = 0; nf < 2; ++nf) {
        const int row = wn * 64 + nf * 32 + l31;
        const unsigned m = (unsigned)((((row & 7) ^ ((row >> 3) & 7))) << 4);
        bbx[nf] = 32768u | (unsigned)(row * 128) | m;
    }

    // ---- stage streams: global source column applies the same involution ----
    const int r0 = tid >> 3;
    const int m0 = (r0 & 7) ^ ((r0 >> 3) & 7);
    const int c0 = ((tid & 7) ^ m0) << 3;
    const int ci1 = 512 + tid;
    const int r1 = ci1 >> 3;
    const int m1 = (r1 & 7) ^ ((r1 >> 3) & 7);
    const int c1 = ((ci1 & 7) ^ m1) << 3;

    const unsigned short* asrc[2][2];
    const unsigned short* bsrc[2][2];
    unsigned adst[2][2], bdst[2][2];
    #pragma unroll
    for (int hh = 0; hh < 2; ++hh) {
        asrc[hh][0] = Xb + (size_t)(arow0 + hh * 128 + r0) * K + BK + c0;   // A(t+1)
        asrc[hh][1] = Xb + (size_t)(arow0 + hh * 128 + (r1 & 63) + 64) * K + BK + c1;
        bsrc[hh][0] = Qb + (size_t)(brow0 + hh * 128 + r0) * K + BK + c0;   // B(t+1)
        bsrc[hh][1] = Qb + (size_t)(brow0 + hh * 128 + (r1 & 63) + 64) * K + BK + c1;
        adst[hh][0] = (unsigned)(hh * 16384 + tid * 16);
        adst[hh][1] = (unsigned)(hh * 16384 + ci1 * 16);
        bdst[hh][0] = (unsigned)(32768 + hh * 16384 + tid * 16);
        bdst[hh][1] = (unsigned)(32768 + hh * 16384 + ci1 * 16);
    }

    // ---- prologue: stage tile 0 {A0,A1,B0,B1} into buffer 0 ----
    #pragma unroll
    for (int hh = 0; hh < 2; ++hh) {
        const unsigned short* ga0 = Xb + (size_t)(arow0 + hh * 128 + r0) * K + c0;
        const unsigned short* ga1 = Xb + (size_t)(arow0 + hh * 128 + (r1 & 63) + 64) * K + c1;
        const unsigned short* gb0 = Qb + (size_t)(brow0 + hh * 128 + r0) * K + c0;
        const unsigned short* gb1 = Qb + (size_t)(brow0 + hh * 128 + (r1 & 63) + 64) * K + c1;
        __builtin_amdgcn_global_load_lds(GLOBAL_CAST(ga0), LDS_CAST(lds + adst[hh][0]), 16, 0, 0);
        __builtin_amdgcn_global_load_lds(GLOBAL_CAST(ga1), LDS_CAST(lds + adst[hh][1]), 16, 0, 0);
        __builtin_amdgcn_global_load_lds(GLOBAL_CAST(gb0), LDS_CAST(lds + bdst[hh][0]), 16, 0, 0);
        __builtin_amdgcn_global_load_lds(GLOBAL_CAST(gb1), LDS_CAST(lds + bdst[hh][1]), 16, 0, 0);
    }
    asm volatile("s_waitcnt vmcnt(0)" ::: "memory");
    __builtin_amdgcn_sched_barrier(0);
    __builtin_amdgcn_s_barrier();

    f32x16 acc[4][2] = {};
    bf16x8 aX[4], bX[2], aY[4], bY[2];

    #define RDSLICE(AV, BV, KS) {                                               \
        _Pragma("unroll")                                                       \
        for (int mf = 0; mf < 4; ++mf)                                          \
            AV[mf] = *(const bf16x8*)(lds + ((tb | abx[mf]) ^ ksel[KS]));       \
        _Pragma("unroll")                                                       \
        for (int nf = 0; nf < 2; ++nf)                                          \
            BV[nf] = *(const bf16x8*)(lds + ((tb | bbx[nf]) ^ ksel[KS])); }
    #define MFMA8(AV, BV)                                                       \
        _Pragma("unroll")                                                       \
        for (int mf = 0; mf < 4; ++mf)                                          \
            _Pragma("unroll")                                                   \
            for (int nf = 0; nf < 2; ++nf)                                      \
                acc[mf][nf] = __builtin_amdgcn_mfma_f32_32x32x16_bf16(          \
                    AV[mf], BV[nf], acc[mf][nf], 0, 0, 0);

    for (int t = 0; t < NT; ++t) {
        const unsigned tb = (unsigned)(t & 1) << 16;
        const unsigned ta = tb ^ 0x10000u;
        const bool doS = (t < NT - 1);

        // ================= section A =================
        if (doS) {
            #pragma unroll
            for (int hh = 0; hh < 2; ++hh) {
                __builtin_amdgcn_global_load_lds(GLOBAL_CAST(asrc[hh][0]), LDS_CAST(lds + (ta | adst[hh][0])), 16, 0, 0);
                __builtin_amdgcn_global_load_lds(GLOBAL_CAST(asrc[hh][1]), LDS_CAST(lds + (ta | adst[hh][1])), 16, 0, 0);
            }
        }
        RDSLICE(aX, bX, 0)
        __builtin_amdgcn_s_setprio(1);
        MFMA8(aX, bX)
        __builtin_amdgcn_s_setprio(0);

        if (doS) {
            #pragma unroll
            for (int hh = 0; hh < 2; ++hh) {
                __builtin_amdgcn_global_load_lds(GLOBAL_CAST(bsrc[hh][0]), LDS_CAST(lds + (ta | bdst[hh][0])), 16, 0, 0);
                __builtin_amdgcn_global_load_lds(GLOBAL_CAST(bsrc[hh][1]), LDS_CAST(lds + (ta | bdst[hh][1])), 16, 0, 0);
            }
        }
        RDSLICE(aY, bY, 1)
        __builtin_amdgcn_s_setprio(1);
        MFMA8(aY, bY)
        __builtin_amdgcn_s_setprio(0);

        __builtin_amdgcn_s_barrier();

        // ================= section B =================
        RDSLICE(aX, bX, 2)
        __builtin_amdgcn_s_setprio(1);
        MFMA8(aX, bX)
        __builtin_amdgcn_s_setprio(0);

        RDSLICE(aY, bY, 3)
        __builtin_amdgcn_s_setprio(1);
        MFMA8(aY, bY)
        __builtin_amdgcn_s_setprio(0);

        // advance stage streams (BK elements = 128 B)
        #pragma unroll
        for (int hh = 0; hh < 2; ++hh) {
            asrc[hh][0] += BK; asrc[hh][1] += BK;
            bsrc[hh][0] += BK; bsrc[hh][1] += BK;
        }
        asm volatile("s_waitcnt vmcnt(0)" ::: "memory");
        __builtin_amdgcn_sched_barrier(0);
        __builtin_amdgcn_s_barrier();
    }
    #undef RDSLICE
    #undef MFMA8

    // epilogue: out = scale[n]*acc + bias[n]
    // C/D: col = lane&31, row = (reg&3) + 8*(reg>>2) + 4*(lane>>5)
    #pragma unroll
    for (int nf = 0; nf < 2; ++nf) {
        const int gn = brow0 + wn * 64 + nf * 32 + l31;
        const float sc = scale[gn];
        const float bs = bias[gn];
        #pragma unroll
        for (int mf = 0; mf < 4; ++mf) {
            const size_t gm0 = (size_t)arow0 + wm * 128 + mf * 32 + ((lane >> 5) << 2);
            #pragma unroll
            for (int reg = 0; reg < 16; ++reg) {
                const int row = (reg & 3) + ((reg >> 2) << 3);
                out[(gm0 + row) * (size_t)N + gn] = acc[mf][nf][reg] * sc + bs;
            }
        }
    }
}

// ---------------------------------------------------------------------------
// Fallback: fp32 smem-tiled GEMM, quantize on the fly.
// ---------------------------------------------------------------------------
__global__ __launch_bounds__(256) void fb_gemm_kernel(
    const float* __restrict__ X, const float* __restrict__ W,
    const float* __restrict__ scale, const float* __restrict__ bias,
    float* __restrict__ out, int M, int N, int K)
{
    __shared__ float xs[16][16];
    __shared__ float qs[16][17];
    const int tx = threadIdx.x & 15, ty = threadIdx.x >> 4;
    const int m = blockIdx.y * 16 + ty;
    const int n = blockIdx.x * 16 + tx;
    const int nrow = blockIdx.x * 16 + ty;
    const int mL = min(m, M - 1);
    const int nrowL = min(nrow, N - 1);
    const float thr = scale[nrowL] * 0.75f;
    float acc = 0.f;
    for (int k0 = 0; k0 < K; k0 += 16) {
        xs[ty][tx] = X[(size_t)mL * K + k0 + tx];
        const float w = W[(size_t)nrowL * K + k0 + tx];
        qs[ty][tx] = (w >= thr) ? 1.f : ((w <= -thr) ? -1.f : 0.f);
        __syncthreads();
        #pragma unroll
        for (int kk = 0; kk < 16; ++kk) acc += xs[ty][kk] * qs[tx][kk];
        __syncthreads();
    }
    if (m < M && n < N) out[(size_t)m * N + n] = scale[n] * acc + bias[n];
}

// ---------------------------------------------------------------------------
extern "C" void kernel_launch(void* const* d_in, const int* in_sizes, int n_in,
                              void* d_out, int out_size, void* d_ws, size_t ws_size,
                              hipStream_t stream)
{
    const float* x    = (const float*)d_in[0];
    const float* w    = (const float*)d_in[1];
    const float* bias = (const float*)d_in[2];
    float* out = (float*)d_out;

    const int N = in_sizes[2];             // OUT
    const int K = in_sizes[1] / N;         // IN
    const int M = in_sizes[0] / K;         // B

    const size_t scaleBytes = (size_t)N * sizeof(float);
    const size_t qOff = (scaleBytes + 255) & ~(size_t)255;
    const size_t xOff = qOff + (size_t)N * K * sizeof(unsigned short);
    const size_t need = xOff + (size_t)M * K * sizeof(unsigned short);

    float* scale = (float*)d_ws;

    const bool fast = (ws_size >= need) &&
                      (M % BM == 0) && (N % BN == 0) && (K % BK == 0) &&
                      (K / BK >= 4) &&
                      (((M / BM) * (N / BN)) % 8 == 0);

    if (fast) {
        unsigned short* q  = (unsigned short*)((char*)d_ws + qOff);
        unsigned short* xb = (unsigned short*)((char*)d_ws + xOff);

        scale_quant_kernel<<<N, 256, 0, stream>>>(w, scale, q, K);

        const long nx = (long)M * K;
        const int cvtBlocks = (int)((nx + 2047) / 2048);
        convert_x_kernel<<<cvtBlocks, 256, 0, stream>>>(x, xb, nx);

        const int grid = (M / BM) * (N / BN);
        gemm256_kernel<<<grid, 512, 0, stream>>>(xb, q, scale, bias, out, M, N, K);
    } else {
        scale_quant_kernel<<<N, 256, 0, stream>>>(w, scale, nullptr, K);
        dim3 g((N + 15) / 16, (M + 15) / 16);
        fb_gemm_kernel<<<g, 256, 0, stream>>>(x, w, scale, bias, out, M, N, K);
    }
}